// Round 6
// baseline (296.030 us; speedup 1.0000x reference)
//
#include <hip/hip_runtime.h>
#include <math.h>

#define B_   16
#define C_   256
#define T_   8192
#define BINS 16
#define NFFT 30
#define NP   8          // K-split count

typedef __attribute__((ext_vector_type(8))) _Float16 f16x8;
typedef __attribute__((ext_vector_type(4))) _Float16 f16x4;
typedef __attribute__((ext_vector_type(4))) float f32x4;

// ---------------- Kernel 1: Gram partials via single-fp16 MFMA ----------------
// G = X X^T with x cast to fp16 (rel err 2^-11 -> delta(score) ~ 4e-3, OK).
// Grid (8 tiles of 128x64, 16 b, NP ks) = 1024 blocks, 512 thr = 32 waves/CU.
#define GLSTR 40   // 32 k-elems + 8 pad (half units)

__global__ __launch_bounds__(512) void gram_mfma(const float* __restrict__ x,
                                                 float* __restrict__ gp) {
  const int tile = blockIdx.x;  // ti = tile>>2 (128-row blk), tj = tile&3 (64-col blk)
  const int b    = blockIdx.y;
  const int ks   = blockIdx.z;
  const int ti   = tile >> 2;
  const int tj   = tile & 3;

  __shared__ _Float16 As[128*GLSTR];
  __shared__ _Float16 Bs[64*GLSTR];

  const int tid  = threadIdx.x;
  const int lane = tid & 63;
  const int w    = tid >> 6;       // 0..7
  const int wr   = w >> 2;         // 0..1  (64-row block)
  const int wc   = w & 3;          // 0..3  (16-col block)
  const int fr   = lane & 15;      // row within 16-tile
  const int g    = lane >> 4;      // k-seg group 0..3

  const float* xa = x + ((size_t)(b * C_ + ti * 128)) * T_;
  const float* xb = x + ((size_t)(b * C_ + tj * 64)) * T_;
  const int t0 = ks * (T_ / NP);

  f32x4 acc[4];
#pragma unroll
  for (int mt = 0; mt < 4; ++mt) acc[mt] = (f32x4){0.f, 0.f, 0.f, 0.f};

  // fragment read offsets (swizzle-aware), in half elems
  int aoff[4], boff;
#pragma unroll
  for (int mt = 0; mt < 4; ++mt) {
    const int row = wr*64 + mt*16 + fr;
    aoff[mt] = row*GLSTR + ((g ^ ((row >> 3) & 3)) << 3);
  }
  {
    const int row = wc*16 + fr;
    boff = row*GLSTR + ((g ^ ((row >> 3) & 3)) << 3);
  }

  for (int kt = 0; kt < T_ / NP; kt += 32) {
    // stage A: 128 rows x 32 k (fp32 -> fp16), 2 float4 per thread
#pragma unroll
    for (int h = 0; h < 2; ++h) {
      const int idx = tid + h*512;          // 0..1023
      const int row = idx >> 3;             // 0..127
      const int seg = idx & 7;              // float4 segment
      const int k4s = seg ^ (((row >> 3) & 3) << 1);
      const float4 v = *(const float4*)(xa + (size_t)row*T_ + t0 + kt + seg*4);
      f16x4 hv; hv[0]=(_Float16)v.x; hv[1]=(_Float16)v.y; hv[2]=(_Float16)v.z; hv[3]=(_Float16)v.w;
      *(f16x4*)&As[row*GLSTR + k4s*4] = hv;
    }
    // stage B: 64 rows x 32 k, 1 float4 per thread
    {
      const int row = tid >> 3;             // 0..63
      const int seg = tid & 7;
      const int k4s = seg ^ (((row >> 3) & 3) << 1);
      const float4 v = *(const float4*)(xb + (size_t)row*T_ + t0 + kt + seg*4);
      f16x4 hv; hv[0]=(_Float16)v.x; hv[1]=(_Float16)v.y; hv[2]=(_Float16)v.z; hv[3]=(_Float16)v.w;
      *(f16x4*)&Bs[row*GLSTR + k4s*4] = hv;
    }
    __syncthreads();

    f16x8 fa[4], fb;
#pragma unroll
    for (int mt = 0; mt < 4; ++mt) fa[mt] = *(const f16x8*)&As[aoff[mt]];
    fb = *(const f16x8*)&Bs[boff];
#pragma unroll
    for (int mt = 0; mt < 4; ++mt)
      acc[mt] = __builtin_amdgcn_mfma_f32_16x16x32_f16(fa[mt], fb, acc[mt], 0, 0, 0);
    __syncthreads();
  }

  float* gpart = gp + ((size_t)(ks * 16 + b)) * 65536;
#pragma unroll
  for (int mt = 0; mt < 4; ++mt)
#pragma unroll
    for (int r = 0; r < 4; ++r) {
      const int gi = ti*128 + wr*64 + mt*16 + g*4 + r;
      const int gj = tj*64 + wc*16 + fr;
      gpart[(size_t)gi*256 + gj] = acc[mt][r];
    }
}

// ---------------- Kernel 2a: reduce NP partials + WkG (128 blocks) ----------------
__global__ __launch_bounds__(256) void attn_a(const float* __restrict__ Wk,
                                              const float* __restrict__ gp,
                                              float* __restrict__ wkg) {
  const int tc = blockIdx.x;   // 0..7 (32-col chunks)
  const int b  = blockIdx.y;
  const int tid = threadIdx.x;
  __shared__ float gl[256*32];

  const float* g0 = gp + (size_t)b*65536 + tc*32;
#pragma unroll
  for (int i = 0; i < 32; ++i) {
    const int idx = i*256 + tid;
    const int r = idx >> 5, cl = idx & 31;
    const size_t off = (size_t)r*256 + cl;
    float s = 0.f;
#pragma unroll
    for (int p = 0; p < NP; ++p) s += g0[off + (size_t)p*1048576];
    gl[r*32 + cl] = s;
  }
  __syncthreads();

  const int cl  = tid & 31;
  const int cc0 = (tid >> 5) * 2;
#pragma unroll
  for (int h = 0; h < 2; ++h) {
    const int cc = cc0 + h;
    float a = 0.f;
    for (int c1 = 0; c1 < 256; c1 += 4) {
      const float4 w4 = *(const float4*)&Wk[cc*256 + c1];
      a += w4.x*gl[(c1+0)*32+cl] + w4.y*gl[(c1+1)*32+cl]
         + w4.z*gl[(c1+2)*32+cl] + w4.w*gl[(c1+3)*32+cl];
    }
    wkg[((size_t)b*16 + cc)*256 + tc*32 + cl] = a;
  }
}

// ---------------- Kernel 2b: scores -> softmax -> M = P @ Wv ----------------
__global__ __launch_bounds__(256) void attn_b(const float* __restrict__ Wq,
                                              const float* __restrict__ Wv,
                                              const float* __restrict__ wkg,
                                              float* __restrict__ Mout) {
  const int b = blockIdx.x;
  const int tid = threadIdx.x;
  __shared__ float s1[16*256];
  __shared__ float s2[16*256];
  __shared__ float invs[16];

#pragma unroll
  for (int cc = 0; cc < 16; ++cc) s1[cc*256 + tid] = wkg[((size_t)b*16 + cc)*256 + tid];
  __syncthreads();

  float sc[16];
#pragma unroll
  for (int cc = 0; cc < 16; ++cc) sc[cc] = 0.f;
  for (int c4 = 0; c4 < 64; ++c4) {
    const float4 wq4 = *(const float4*)&Wq[(size_t)tid*256 + c4*4];
#pragma unroll
    for (int cc = 0; cc < 16; ++cc) {
      const float4 p4 = *(const float4*)&s1[cc*256 + c4*4];
      sc[cc] += p4.x*wq4.x + p4.y*wq4.y + p4.z*wq4.z + p4.w*wq4.w;
    }
  }
#pragma unroll
  for (int cc = 0; cc < 16; ++cc) s2[cc*256 + tid] = sc[cc] * 0.0625f;
  __syncthreads();

  // parallel softmax: 16 rows x 16 lanes
  {
    const int rr = tid >> 4, jj = tid & 15;
    float mx = -1e30f;
    for (int c = jj; c < 256; c += 16) mx = fmaxf(mx, s2[rr*256 + c]);
    for (int o = 1; o < 16; o <<= 1) mx = fmaxf(mx, __shfl_xor(mx, o, 64));
    float sm = 0.f;
    for (int c = jj; c < 256; c += 16) {
      const float e = __expf(s2[rr*256 + c] - mx);
      s2[rr*256 + c] = e;
      sm += e;
    }
    for (int o = 1; o < 16; o <<= 1) sm += __shfl_xor(sm, o, 64);
    if (jj == 0) invs[rr] = 1.f / sm;
  }
  __syncthreads();

  float mac[16];
#pragma unroll
  for (int cc = 0; cc < 16; ++cc) mac[cc] = 0.f;
  for (int c4 = 0; c4 < 64; ++c4) {
    float wv[4];
#pragma unroll
    for (int j = 0; j < 4; ++j) wv[j] = Wv[(size_t)(c4*4 + j)*256 + tid];
#pragma unroll
    for (int cc = 0; cc < 16; ++cc) {
      const float4 p4 = *(const float4*)&s2[cc*256 + c4*4];
      mac[cc] += p4.x*wv[0] + p4.y*wv[1] + p4.z*wv[2] + p4.w*wv[3];
    }
  }
#pragma unroll
  for (int cc = 0; cc < 16; ++cc)
    Mout[(size_t)b*4096 + cc*256 + tid] = mac[cc] * invs[cc];
}

// ---------------- Kernel 3: seq = M @ X  (256 blocks, float2) ----------------
__global__ __launch_bounds__(256) void outp_kernel(const float* __restrict__ x,
                                                   const float* __restrict__ M,
                                                   float* __restrict__ seq) {
  const int tc = blockIdx.x;   // 0..15
  const int b  = blockIdx.y;
  const int tid = threadIdx.x;
  const int t  = tc*512 + tid*2;
  const float* xb = x + (size_t)b*C_*T_ + t;
  const float* mb = M + (size_t)b*4096;
  float2 a[16];
#pragma unroll
  for (int cc = 0; cc < 16; ++cc) a[cc] = make_float2(0.f, 0.f);
  for (int ch = 0; ch < 64; ++ch) {
    float2 xv[4];
#pragma unroll
    for (int j = 0; j < 4; ++j)
      xv[j] = *(const float2*)(xb + (size_t)(ch*4 + j) * T_);
#pragma unroll
    for (int cc = 0; cc < 16; ++cc) {
      const float4 m4 = *(const float4*)(mb + cc*256 + ch*4);   // wave-uniform
      a[cc].x += m4.x*xv[0].x + m4.y*xv[1].x + m4.z*xv[2].x + m4.w*xv[3].x;
      a[cc].y += m4.x*xv[0].y + m4.y*xv[1].y + m4.z*xv[2].y + m4.w*xv[3].y;
    }
  }
#pragma unroll
  for (int cc = 0; cc < 16; ++cc)
    *(float2*)(seq + (size_t)(b*16 + cc)*T_ + t) = a[cc];
}

// ---------------- Kernel 4: windowed-DFT power spectrogram ----------------
__global__ __launch_bounds__(256) void spec_kernel(const float* __restrict__ seq,
                                                   float* __restrict__ out) {
  const int tcx = blockIdx.x;  // 0..31
  const int r   = blockIdx.y;  // 0..255
  const int tid = threadIdx.x;
  const int t0  = tcx * 256;

  __shared__ float smem[288];
  __shared__ float ctab[BINS*NFFT];
  __shared__ float stab[BINS*NFFT];

  const float* row = seq + (size_t)r * T_;
  for (int i = tid; i < 288; i += 256) {
    int gg = t0 - 15 + i;
    if (gg < 0) gg = -gg;
    if (gg > T_-1) gg = 2*(T_-1) - gg;
    smem[i] = row[gg];
  }
  for (int i = tid; i < BINS*NFFT; i += 256) {
    const int k = i / NFFT, n = i % NFFT;
    const float TWO_PI = 6.283185307179586f;
    const float wn = 0.5f - 0.5f * cosf(TWO_PI * (float)n / (float)NFFT);
    const float ang = TWO_PI * (float)(k * n) / (float)NFFT;
    ctab[i] = cosf(ang) * wn;
    stab[i] = sinf(ang) * wn;
  }
  __syncthreads();

  const int k   = tid >> 4;
  const int sub = tid & 15;
  float cr[NFFT], ci[NFFT];
#pragma unroll
  for (int n = 0; n < NFFT; ++n) { cr[n] = ctab[k*NFFT + n]; ci[n] = stab[k*NFFT + n]; }

  float* orow = out + (size_t)(r*BINS + k) * T_ + t0;
  const float inv_norm = 1.0f / 11.25f;

  for (int jj = 0; jj < 4; ++jj) {
    const int x0 = 4*sub + 64*jj;
    float smp[36];
#pragma unroll
    for (int q = 0; q < 9; ++q) {
      const float4 v = *(const float4*)&smem[x0 + 4*q];
      smp[4*q+0] = v.x; smp[4*q+1] = v.y; smp[4*q+2] = v.z; smp[4*q+3] = v.w;
    }
    float4 pw;
#pragma unroll
    for (int p = 0; p < 4; ++p) {
      float re = 0.f, im = 0.f;
#pragma unroll
      for (int n = 0; n < NFFT; ++n) {
        re += cr[n] * smp[p + n];
        im += ci[n] * smp[p + n];
      }
      ((float*)&pw)[p] = (re*re + im*im) * inv_norm;
    }
    *(float4*)(orow + x0) = pw;
  }
}

// ---------------- launch ----------------
extern "C" void kernel_launch(void* const* d_in, const int* in_sizes, int n_in,
                              void* d_out, int out_size, void* d_ws, size_t ws_size,
                              hipStream_t stream) {
  const float* x  = (const float*)d_in[0];
  const float* Wk = (const float*)d_in[1];
  const float* Wq = (const float*)d_in[2];
  const float* Wv = (const float*)d_in[3];
  float* out = (float*)d_out;
  float* ws  = (float*)d_ws;

  float* gp  = ws;                         // NP*16*65536 = 33.6 MB (NP=8)
  float* wkg = ws + (size_t)NP*1048576;    // 16*16*256
  float* M   = wkg + 65536;                // 16*16*256
  float* seq = M + 65536;                  // 256*8192 = 8.39 MB

  gram_mfma<<<dim3(8, 16, NP), 512, 0, stream>>>(x, gp);
  attn_a<<<dim3(8, 16), 256, 0, stream>>>(Wk, gp, wkg);
  attn_b<<<dim3(16), 256, 0, stream>>>(Wq, Wv, wkg, M);
  outp_kernel<<<dim3(16, 16), 256, 0, stream>>>(x, M, seq);
  spec_kernel<<<dim3(32, 256), 256, 0, stream>>>(seq, out);
}

// Round 8
// 234.511 us; speedup vs baseline: 1.2623x; 1.2623x over previous
//
#include <hip/hip_runtime.h>
#include <math.h>

#define B_   16
#define C_   256
#define T_   8192
#define BINS 16
#define NFFT 30

typedef __attribute__((ext_vector_type(8))) _Float16 f16x8;
typedef __attribute__((ext_vector_type(2))) __fp16 fp16x2;
typedef __attribute__((ext_vector_type(4))) float f32x4;

typedef const __attribute__((address_space(1))) unsigned int ga_u32;
typedef __attribute__((address_space(3))) unsigned int ls_u32;

union f16pack { f16x8 v; fp16x2 p[4]; };

// ---------------- Kernel 1: Gram via fp16 MFMA, shared-panel staging ----------------
// Block (ti, b, ks): G rows [ti*128,+128) x cols [0,256) for K-chunk ks.
// One 256-row x 32-k fp32 panel per step serves BOTH A and B operands.
// global_load_lds staging (linear LDS, source-XOR swizzle seg^=row&7),
// double-buffered 2-phase: STAGE(next) -> compute(cur) -> syncthreads.

static __device__ __forceinline__ void stage_panel(float* dstbase, const float* xb,
                                                   int koff, int tid) {
#pragma unroll
  for (int h = 0; h < 4; ++h) {
    const int idx = h*512 + tid;       // 0..2047 -> 2048 x 16B = 32 KB
    const int row = idx >> 3;          // 0..255
    const int ps  = idx & 7;           // physical 16B segment in row
    const int ls  = ps ^ (row & 7);    // logical segment (involution)
    const float* src = xb + (size_t)row*T_ + koff + ls*4;
    __builtin_amdgcn_global_load_lds((ga_u32*)src, (ls_u32*)(dstbase + idx*4), 16, 0, 0);
  }
}

template<int NPT>
__global__ __launch_bounds__(512, 4) void gram_mfma(const float* __restrict__ x,
                                                    float* __restrict__ gp) {
  const int ti = blockIdx.x;   // 0..1
  const int b  = blockIdx.y;
  const int ks = blockIdx.z;
  constexpr int KCH = T_ / NPT;

  __shared__ float P[2][256*32];   // 2 x 32 KB

  const int tid  = threadIdx.x;
  const int lane = tid & 63;
  const int w    = tid >> 6;       // 0..7
  const int wr   = w >> 2;         // 0..1 (64-row block)
  const int wc   = w & 3;          // 0..3 (64-col block)
  const int fr   = lane & 15;
  const int g    = lane >> 4;      // k-group (k = g*8 + j)

  const float* xb = x + ((size_t)b * C_) * T_;
  const int t0 = ks * KCH;

  f32x4 acc[4][4];
#pragma unroll
  for (int mt = 0; mt < 4; ++mt)
#pragma unroll
    for (int nt = 0; nt < 4; ++nt) acc[mt][nt] = (f32x4){0.f, 0.f, 0.f, 0.f};

  stage_panel(P[0], xb, t0, tid);
  __syncthreads();

  int cur = 0;
  for (int kt = 0; kt < KCH; kt += 32) {
    if (kt + 32 < KCH) stage_panel(P[cur ^ 1], xb, t0 + kt + 32, tid);

    const float* Pc = P[cur];
    f16pack fb[4];
#pragma unroll
    for (int nt = 0; nt < 4; ++nt) {
      const int r = wc*64 + nt*16 + fr;
      const float4 lo = *(const float4*)&Pc[r*32 + (((2*g+0) ^ (r&7))<<2)];
      const float4 hi = *(const float4*)&Pc[r*32 + (((2*g+1) ^ (r&7))<<2)];
      fb[nt].p[0] = __builtin_amdgcn_cvt_pkrtz(lo.x, lo.y);
      fb[nt].p[1] = __builtin_amdgcn_cvt_pkrtz(lo.z, lo.w);
      fb[nt].p[2] = __builtin_amdgcn_cvt_pkrtz(hi.x, hi.y);
      fb[nt].p[3] = __builtin_amdgcn_cvt_pkrtz(hi.z, hi.w);
    }
#pragma unroll
    for (int mt = 0; mt < 4; ++mt) {
      const int r = ti*128 + wr*64 + mt*16 + fr;
      const float4 lo = *(const float4*)&Pc[r*32 + (((2*g+0) ^ (r&7))<<2)];
      const float4 hi = *(const float4*)&Pc[r*32 + (((2*g+1) ^ (r&7))<<2)];
      f16pack fa;
      fa.p[0] = __builtin_amdgcn_cvt_pkrtz(lo.x, lo.y);
      fa.p[1] = __builtin_amdgcn_cvt_pkrtz(lo.z, lo.w);
      fa.p[2] = __builtin_amdgcn_cvt_pkrtz(hi.x, hi.y);
      fa.p[3] = __builtin_amdgcn_cvt_pkrtz(hi.z, hi.w);
#pragma unroll
      for (int nt = 0; nt < 4; ++nt)
        acc[mt][nt] = __builtin_amdgcn_mfma_f32_16x16x32_f16(fa.v, fb[nt].v, acc[mt][nt], 0, 0, 0);
    }
    __syncthreads();
    cur ^= 1;
  }

  float* gpart = gp + ((size_t)(ks * 16 + b)) * 65536;
#pragma unroll
  for (int mt = 0; mt < 4; ++mt)
#pragma unroll
    for (int nt = 0; nt < 4; ++nt)
#pragma unroll
      for (int r = 0; r < 4; ++r) {
        const int gi = ti*128 + wr*64 + mt*16 + g*4 + r;
        const int gj = wc*64 + nt*16 + fr;
        gpart[(size_t)gi*256 + gj] = acc[mt][nt][r];
      }
}

// ---------------- Kernel 2a: reduce NPT partials + WkG (128 blocks) ----------------
template<int NPT>
__global__ __launch_bounds__(256) void attn_a_t(const float* __restrict__ Wk,
                                                const float* __restrict__ gp,
                                                float* __restrict__ wkg) {
  const int tc = blockIdx.x;   // 0..7 (32-col chunks)
  const int b  = blockIdx.y;
  const int tid = threadIdx.x;
  __shared__ float gl[256*32];

  const float* g0 = gp + (size_t)b*65536 + tc*32;
#pragma unroll
  for (int i = 0; i < 32; ++i) {
    const int idx = i*256 + tid;
    const int r = idx >> 5, cl = idx & 31;
    const size_t off = (size_t)r*256 + cl;
    float s = 0.f;
#pragma unroll
    for (int p = 0; p < NPT; ++p) s += g0[off + (size_t)p*1048576];
    gl[r*32 + cl] = s;
  }
  __syncthreads();

  const int cl  = tid & 31;
  const int cc0 = (tid >> 5) * 2;
#pragma unroll
  for (int h = 0; h < 2; ++h) {
    const int cc = cc0 + h;
    float a = 0.f;
    for (int c1 = 0; c1 < 256; c1 += 4) {
      const float4 w4 = *(const float4*)&Wk[cc*256 + c1];
      a += w4.x*gl[(c1+0)*32+cl] + w4.y*gl[(c1+1)*32+cl]
         + w4.z*gl[(c1+2)*32+cl] + w4.w*gl[(c1+3)*32+cl];
    }
    wkg[((size_t)b*16 + cc)*256 + tc*32 + cl] = a;
  }
}

// ---------------- Kernel 2b: scores -> softmax -> M = P @ Wv ----------------
__global__ __launch_bounds__(256) void attn_b(const float* __restrict__ Wq,
                                              const float* __restrict__ Wv,
                                              const float* __restrict__ wkg,
                                              float* __restrict__ Mout) {
  const int b = blockIdx.x;
  const int tid = threadIdx.x;
  __shared__ float s1[16*256];
  __shared__ float s2[16*256];
  __shared__ float invs[16];

#pragma unroll
  for (int cc = 0; cc < 16; ++cc) s1[cc*256 + tid] = wkg[((size_t)b*16 + cc)*256 + tid];
  __syncthreads();

  float sc[16];
#pragma unroll
  for (int cc = 0; cc < 16; ++cc) sc[cc] = 0.f;
  for (int c4 = 0; c4 < 64; ++c4) {
    const float4 wq4 = *(const float4*)&Wq[(size_t)tid*256 + c4*4];
#pragma unroll
    for (int cc = 0; cc < 16; ++cc) {
      const float4 p4 = *(const float4*)&s1[cc*256 + c4*4];
      sc[cc] += p4.x*wq4.x + p4.y*wq4.y + p4.z*wq4.z + p4.w*wq4.w;
    }
  }
#pragma unroll
  for (int cc = 0; cc < 16; ++cc) s2[cc*256 + tid] = sc[cc] * 0.0625f;
  __syncthreads();

  {
    const int rr = tid >> 4, jj = tid & 15;
    float mx = -1e30f;
    for (int c = jj; c < 256; c += 16) mx = fmaxf(mx, s2[rr*256 + c]);
    for (int o = 1; o < 16; o <<= 1) mx = fmaxf(mx, __shfl_xor(mx, o, 64));
    float sm = 0.f;
    for (int c = jj; c < 256; c += 16) {
      const float e = __expf(s2[rr*256 + c] - mx);
      s2[rr*256 + c] = e;
      sm += e;
    }
    for (int o = 1; o < 16; o <<= 1) sm += __shfl_xor(sm, o, 64);
    if (jj == 0) invs[rr] = 1.f / sm;
  }
  __syncthreads();

  float mac[16];
#pragma unroll
  for (int cc = 0; cc < 16; ++cc) mac[cc] = 0.f;
  for (int c4 = 0; c4 < 64; ++c4) {
    float wv[4];
#pragma unroll
    for (int j = 0; j < 4; ++j) wv[j] = Wv[(size_t)(c4*4 + j)*256 + tid];
#pragma unroll
    for (int cc = 0; cc < 16; ++cc) {
      const float4 p4 = *(const float4*)&s2[cc*256 + c4*4];
      mac[cc] += p4.x*wv[0] + p4.y*wv[1] + p4.z*wv[2] + p4.w*wv[3];
    }
  }
#pragma unroll
  for (int cc = 0; cc < 16; ++cc)
    Mout[(size_t)b*4096 + cc*256 + tid] = mac[cc] * invs[cc];
}

// ---------------- Kernel 3: seq = M @ X  (256 blocks, float2) ----------------
__global__ __launch_bounds__(256) void outp_kernel(const float* __restrict__ x,
                                                   const float* __restrict__ M,
                                                   float* __restrict__ seq) {
  const int tc = blockIdx.x;   // 0..15
  const int b  = blockIdx.y;
  const int tid = threadIdx.x;
  const int t  = tc*512 + tid*2;
  const float* xb = x + (size_t)b*C_*T_ + t;
  const float* mb = M + (size_t)b*4096;
  float2 a[16];
#pragma unroll
  for (int cc = 0; cc < 16; ++cc) a[cc] = make_float2(0.f, 0.f);
  for (int ch = 0; ch < 64; ++ch) {
    float2 xv[4];
#pragma unroll
    for (int j = 0; j < 4; ++j)
      xv[j] = *(const float2*)(xb + (size_t)(ch*4 + j) * T_);
#pragma unroll
    for (int cc = 0; cc < 16; ++cc) {
      const float4 m4 = *(const float4*)(mb + cc*256 + ch*4);
      a[cc].x += m4.x*xv[0].x + m4.y*xv[1].x + m4.z*xv[2].x + m4.w*xv[3].x;
      a[cc].y += m4.x*xv[0].y + m4.y*xv[1].y + m4.z*xv[2].y + m4.w*xv[3].y;
    }
  }
#pragma unroll
  for (int cc = 0; cc < 16; ++cc)
    *(float2*)(seq + (size_t)(b*16 + cc)*T_ + t) = a[cc];
}

// ---------------- Kernel 4: windowed-DFT power spectrogram ----------------
__global__ __launch_bounds__(256) void spec_kernel(const float* __restrict__ seq,
                                                   float* __restrict__ out) {
  const int tcx = blockIdx.x;  // 0..31
  const int r   = blockIdx.y;  // 0..255
  const int tid = threadIdx.x;
  const int t0  = tcx * 256;

  __shared__ float smem[288];
  __shared__ float ctab[BINS*NFFT];
  __shared__ float stab[BINS*NFFT];

  const float* row = seq + (size_t)r * T_;
  for (int i = tid; i < 288; i += 256) {
    int gg = t0 - 15 + i;
    if (gg < 0) gg = -gg;
    if (gg > T_-1) gg = 2*(T_-1) - gg;
    smem[i] = row[gg];
  }
  for (int i = tid; i < BINS*NFFT; i += 256) {
    const int k = i / NFFT, n = i % NFFT;
    const float TWO_PI = 6.283185307179586f;
    const float wn = 0.5f - 0.5f * cosf(TWO_PI * (float)n / (float)NFFT);
    const float ang = TWO_PI * (float)(k * n) / (float)NFFT;
    ctab[i] = cosf(ang) * wn;
    stab[i] = sinf(ang) * wn;
  }
  __syncthreads();

  const int k   = tid >> 4;
  const int sub = tid & 15;
  float cr[NFFT], ci[NFFT];
#pragma unroll
  for (int n = 0; n < NFFT; ++n) { cr[n] = ctab[k*NFFT + n]; ci[n] = stab[k*NFFT + n]; }

  float* orow = out + (size_t)(r*BINS + k) * T_ + t0;
  const float inv_norm = 1.0f / 11.25f;

  for (int jj = 0; jj < 4; ++jj) {
    const int x0 = 4*sub + 64*jj;
    float smp[36];
#pragma unroll
    for (int q = 0; q < 9; ++q) {
      const float4 v = *(const float4*)&smem[x0 + 4*q];
      smp[4*q+0] = v.x; smp[4*q+1] = v.y; smp[4*q+2] = v.z; smp[4*q+3] = v.w;
    }
    float4 pw;
#pragma unroll
    for (int p = 0; p < 4; ++p) {
      float re = 0.f, im = 0.f;
#pragma unroll
      for (int n = 0; n < NFFT; ++n) {
        re += cr[n] * smp[p + n];
        im += ci[n] * smp[p + n];
      }
      ((float*)&pw)[p] = (re*re + im*im) * inv_norm;
    }
    *(float4*)(orow + x0) = pw;
  }
}

// ---------------- launch ----------------
extern "C" void kernel_launch(void* const* d_in, const int* in_sizes, int n_in,
                              void* d_out, int out_size, void* d_ws, size_t ws_size,
                              hipStream_t stream) {
  const float* x  = (const float*)d_in[0];
  const float* Wk = (const float*)d_in[1];
  const float* Wq = (const float*)d_in[2];
  const float* Wv = (const float*)d_in[3];
  float* out = (float*)d_out;
  float* ws  = (float*)d_ws;

  // floats: gp = np*1048576; wkg,M = 65536 each; seq = 2097152
  const size_t tail = 65536ull*2 + 2097152ull;
  const int np = (ws_size >= (16ull*1048576ull + tail) * 4ull) ? 16 : 8;

  float* gp  = ws;
  float* wkg = ws + (size_t)np*1048576;
  float* M   = wkg + 65536;
  float* seq = M + 65536;

  if (np == 16) {
    gram_mfma<16><<<dim3(2, 16, 16), 512, 0, stream>>>(x, gp);
    attn_a_t<16><<<dim3(8, 16), 256, 0, stream>>>(Wk, gp, wkg);
  } else {
    gram_mfma<8><<<dim3(2, 16, 8), 512, 0, stream>>>(x, gp);
    attn_a_t<8><<<dim3(8, 16), 256, 0, stream>>>(Wk, gp, wkg);
  }
  attn_b<<<dim3(16), 256, 0, stream>>>(Wq, Wv, wkg, M);
  outp_kernel<<<dim3(16, 16), 256, 0, stream>>>(x, M, seq);
  spec_kernel<<<dim3(32, 256), 256, 0, stream>>>(seq, out);
}

// Round 9
// 234.461 us; speedup vs baseline: 1.2626x; 1.0002x over previous
//
#include <hip/hip_runtime.h>
#include <math.h>

#define B_   16
#define C_   256
#define T_   8192
#define BINS 16
#define NFFT 30

typedef __attribute__((ext_vector_type(8))) _Float16 f16x8;
typedef __attribute__((ext_vector_type(2))) __fp16 fp16x2;
typedef __attribute__((ext_vector_type(4))) float f32x4;

typedef const __attribute__((address_space(1))) unsigned int ga_u32;
typedef __attribute__((address_space(3))) unsigned int ls_u32;

union f16pack { f16x8 v; fp16x2 p[4]; };

// ---------------- Kernel 0: DFT coefficient tables (once) ----------------
__global__ __launch_bounds__(512) void spec_tables(float* __restrict__ ctab,
                                                   float* __restrict__ stab) {
  const int i = threadIdx.x;
  if (i < BINS*NFFT) {
    const int k = i / NFFT, n = i % NFFT;
    const float TWO_PI = 6.283185307179586f;
    const float wn = 0.5f - 0.5f * cosf(TWO_PI * (float)n / (float)NFFT);
    const float ang = TWO_PI * (float)(k * n) / (float)NFFT;
    ctab[i] = cosf(ang) * wn;
    stab[i] = sinf(ang) * wn;
  }
}

// ---------------- Kernel 1: Gram via fp16 MFMA, shared-panel staging ----------------
// Block (ti, b, ks): G rows [ti*128,+128) x cols [0,256) for K-chunk ks.
// One 256-row x 32-k fp32 panel per step serves BOTH A and B operands.
// global_load_lds staging (linear LDS, source-XOR swizzle seg^=row&7),
// double-buffered 2-phase. Partials stored fp16 (range ~1e2, rel 5e-4: safe).

static __device__ __forceinline__ void stage_panel(float* dstbase, const float* xb,
                                                   int koff, int tid) {
#pragma unroll
  for (int h = 0; h < 4; ++h) {
    const int idx = h*512 + tid;       // 0..2047 -> 2048 x 16B = 32 KB
    const int row = idx >> 3;          // 0..255
    const int ps  = idx & 7;           // physical 16B segment in row
    const int ls  = ps ^ (row & 7);    // logical segment (involution)
    const float* src = xb + (size_t)row*T_ + koff + ls*4;
    __builtin_amdgcn_global_load_lds((ga_u32*)src, (ls_u32*)(dstbase + idx*4), 16, 0, 0);
  }
}

template<int NPT>
__global__ __launch_bounds__(512, 4) void gram_mfma(const float* __restrict__ x,
                                                    _Float16* __restrict__ gp) {
  const int ti = blockIdx.x;   // 0..1
  const int b  = blockIdx.y;
  const int ks = blockIdx.z;
  constexpr int KCH = T_ / NPT;

  __shared__ float P[2][256*32];   // 2 x 32 KB

  const int tid  = threadIdx.x;
  const int lane = tid & 63;
  const int w    = tid >> 6;       // 0..7
  const int wr   = w >> 2;         // 0..1 (64-row block)
  const int wc   = w & 3;          // 0..3 (64-col block)
  const int fr   = lane & 15;
  const int g    = lane >> 4;      // k-group (k = g*8 + j)

  const float* xb = x + ((size_t)b * C_) * T_;
  const int t0 = ks * KCH;

  f32x4 acc[4][4];
#pragma unroll
  for (int mt = 0; mt < 4; ++mt)
#pragma unroll
    for (int nt = 0; nt < 4; ++nt) acc[mt][nt] = (f32x4){0.f, 0.f, 0.f, 0.f};

  stage_panel(P[0], xb, t0, tid);
  __syncthreads();

  int cur = 0;
  for (int kt = 0; kt < KCH; kt += 32) {
    if (kt + 32 < KCH) stage_panel(P[cur ^ 1], xb, t0 + kt + 32, tid);

    const float* Pc = P[cur];
    f16pack fb[4];
#pragma unroll
    for (int nt = 0; nt < 4; ++nt) {
      const int r = wc*64 + nt*16 + fr;
      const float4 lo = *(const float4*)&Pc[r*32 + (((2*g+0) ^ (r&7))<<2)];
      const float4 hi = *(const float4*)&Pc[r*32 + (((2*g+1) ^ (r&7))<<2)];
      fb[nt].p[0] = __builtin_amdgcn_cvt_pkrtz(lo.x, lo.y);
      fb[nt].p[1] = __builtin_amdgcn_cvt_pkrtz(lo.z, lo.w);
      fb[nt].p[2] = __builtin_amdgcn_cvt_pkrtz(hi.x, hi.y);
      fb[nt].p[3] = __builtin_amdgcn_cvt_pkrtz(hi.z, hi.w);
    }
#pragma unroll
    for (int mt = 0; mt < 4; ++mt) {
      const int r = ti*128 + wr*64 + mt*16 + fr;
      const float4 lo = *(const float4*)&Pc[r*32 + (((2*g+0) ^ (r&7))<<2)];
      const float4 hi = *(const float4*)&Pc[r*32 + (((2*g+1) ^ (r&7))<<2)];
      f16pack fa;
      fa.p[0] = __builtin_amdgcn_cvt_pkrtz(lo.x, lo.y);
      fa.p[1] = __builtin_amdgcn_cvt_pkrtz(lo.z, lo.w);
      fa.p[2] = __builtin_amdgcn_cvt_pkrtz(hi.x, hi.y);
      fa.p[3] = __builtin_amdgcn_cvt_pkrtz(hi.z, hi.w);
#pragma unroll
      for (int nt = 0; nt < 4; ++nt)
        acc[mt][nt] = __builtin_amdgcn_mfma_f32_16x16x32_f16(fa.v, fb[nt].v, acc[mt][nt], 0, 0, 0);
    }
    __syncthreads();
    cur ^= 1;
  }

  _Float16* gpart = gp + ((size_t)(ks * 16 + b)) * 65536;
#pragma unroll
  for (int mt = 0; mt < 4; ++mt)
#pragma unroll
    for (int nt = 0; nt < 4; ++nt)
#pragma unroll
      for (int r = 0; r < 4; ++r) {
        const int gi = ti*128 + wr*64 + mt*16 + g*4 + r;
        const int gj = wc*64 + nt*16 + fr;
        gpart[(size_t)gi*256 + gj] = (_Float16)acc[mt][nt][r];
      }
}

// ---------------- Kernel 2a: reduce NPT fp16 partials + WkG (128 blocks) ----------------
template<int NPT>
__global__ __launch_bounds__(256) void attn_a_t(const float* __restrict__ Wk,
                                                const _Float16* __restrict__ gp,
                                                float* __restrict__ wkg) {
  const int tc = blockIdx.x;   // 0..7 (32-col chunks)
  const int b  = blockIdx.y;
  const int tid = threadIdx.x;
  __shared__ float gl[256*32];

  const _Float16* g0 = gp + (size_t)b*65536 + tc*32;
#pragma unroll
  for (int i = 0; i < 32; ++i) {
    const int idx = i*256 + tid;
    const int r = idx >> 5, cl = idx & 31;
    const size_t off = (size_t)r*256 + cl;
    float s = 0.f;
#pragma unroll
    for (int p = 0; p < NPT; ++p) s += (float)g0[off + (size_t)p*1048576];
    gl[r*32 + cl] = s;
  }
  __syncthreads();

  const int cl  = tid & 31;
  const int cc0 = (tid >> 5) * 2;
#pragma unroll
  for (int h = 0; h < 2; ++h) {
    const int cc = cc0 + h;
    float a = 0.f;
    for (int c1 = 0; c1 < 256; c1 += 4) {
      const float4 w4 = *(const float4*)&Wk[cc*256 + c1];
      a += w4.x*gl[(c1+0)*32+cl] + w4.y*gl[(c1+1)*32+cl]
         + w4.z*gl[(c1+2)*32+cl] + w4.w*gl[(c1+3)*32+cl];
    }
    wkg[((size_t)b*16 + cc)*256 + tc*32 + cl] = a;
  }
}

// ---------------- Kernel 2b: scores -> softmax -> M = P @ Wv ----------------
__global__ __launch_bounds__(256) void attn_b(const float* __restrict__ Wq,
                                              const float* __restrict__ Wv,
                                              const float* __restrict__ wkg,
                                              float* __restrict__ Mout) {
  const int b = blockIdx.x;
  const int tid = threadIdx.x;
  __shared__ float s1[16*256];
  __shared__ float s2[16*256];
  __shared__ float invs[16];

#pragma unroll
  for (int cc = 0; cc < 16; ++cc) s1[cc*256 + tid] = wkg[((size_t)b*16 + cc)*256 + tid];
  __syncthreads();

  float sc[16];
#pragma unroll
  for (int cc = 0; cc < 16; ++cc) sc[cc] = 0.f;
  for (int c4 = 0; c4 < 64; ++c4) {
    const float4 wq4 = *(const float4*)&Wq[(size_t)tid*256 + c4*4];
#pragma unroll
    for (int cc = 0; cc < 16; ++cc) {
      const float4 p4 = *(const float4*)&s1[cc*256 + c4*4];
      sc[cc] += p4.x*wq4.x + p4.y*wq4.y + p4.z*wq4.z + p4.w*wq4.w;
    }
  }
#pragma unroll
  for (int cc = 0; cc < 16; ++cc) s2[cc*256 + tid] = sc[cc] * 0.0625f;
  __syncthreads();

  {
    const int rr = tid >> 4, jj = tid & 15;
    float mx = -1e30f;
    for (int c = jj; c < 256; c += 16) mx = fmaxf(mx, s2[rr*256 + c]);
    for (int o = 1; o < 16; o <<= 1) mx = fmaxf(mx, __shfl_xor(mx, o, 64));
    float sm = 0.f;
    for (int c = jj; c < 256; c += 16) {
      const float e = __expf(s2[rr*256 + c] - mx);
      s2[rr*256 + c] = e;
      sm += e;
    }
    for (int o = 1; o < 16; o <<= 1) sm += __shfl_xor(sm, o, 64);
    if (jj == 0) invs[rr] = 1.f / sm;
  }
  __syncthreads();

  float mac[16];
#pragma unroll
  for (int cc = 0; cc < 16; ++cc) mac[cc] = 0.f;
  for (int c4 = 0; c4 < 64; ++c4) {
    float wv[4];
#pragma unroll
    for (int j = 0; j < 4; ++j) wv[j] = Wv[(size_t)(c4*4 + j)*256 + tid];
#pragma unroll
    for (int cc = 0; cc < 16; ++cc) {
      const float4 p4 = *(const float4*)&s2[cc*256 + c4*4];
      mac[cc] += p4.x*wv[0] + p4.y*wv[1] + p4.z*wv[2] + p4.w*wv[3];
    }
  }
#pragma unroll
  for (int cc = 0; cc < 16; ++cc)
    Mout[(size_t)b*4096 + cc*256 + tid] = mac[cc] * invs[cc];
}

// ---------------- Kernel 3: seq = M @ X  (256 blocks, float2) ----------------
__global__ __launch_bounds__(256) void outp_kernel(const float* __restrict__ x,
                                                   const float* __restrict__ M,
                                                   float* __restrict__ seq) {
  const int tc = blockIdx.x;   // 0..15
  const int b  = blockIdx.y;
  const int tid = threadIdx.x;
  const int t  = tc*512 + tid*2;
  const float* xb = x + (size_t)b*C_*T_ + t;
  const float* mb = M + (size_t)b*4096;
  float2 a[16];
#pragma unroll
  for (int cc = 0; cc < 16; ++cc) a[cc] = make_float2(0.f, 0.f);
  for (int ch = 0; ch < 64; ++ch) {
    float2 xv[4];
#pragma unroll
    for (int j = 0; j < 4; ++j)
      xv[j] = *(const float2*)(xb + (size_t)(ch*4 + j) * T_);
#pragma unroll
    for (int cc = 0; cc < 16; ++cc) {
      const float4 m4 = *(const float4*)(mb + cc*256 + ch*4);
      a[cc].x += m4.x*xv[0].x + m4.y*xv[1].x + m4.z*xv[2].x + m4.w*xv[3].x;
      a[cc].y += m4.x*xv[0].y + m4.y*xv[1].y + m4.z*xv[2].y + m4.w*xv[3].y;
    }
  }
#pragma unroll
  for (int cc = 0; cc < 16; ++cc)
    *(float2*)(seq + (size_t)(b*16 + cc)*T_ + t) = a[cc];
}

// ---------------- Kernel 4: windowed-DFT power spectrogram ----------------
__global__ __launch_bounds__(256) void spec_kernel(const float* __restrict__ seq,
                                                   const float* __restrict__ ctabg,
                                                   const float* __restrict__ stabg,
                                                   float* __restrict__ out) {
  const int tcx = blockIdx.x;  // 0..31
  const int r   = blockIdx.y;  // 0..255
  const int tid = threadIdx.x;
  const int t0  = tcx * 256;

  __shared__ float smem[288];
  __shared__ float ctab[BINS*NFFT];
  __shared__ float stab[BINS*NFFT];

  const float* row = seq + (size_t)r * T_;
  for (int i = tid; i < 288; i += 256) {
    int gg = t0 - 15 + i;
    if (gg < 0) gg = -gg;
    if (gg > T_-1) gg = 2*(T_-1) - gg;
    smem[i] = row[gg];
  }
  for (int i = tid; i < BINS*NFFT; i += 256) {
    ctab[i] = ctabg[i];
    stab[i] = stabg[i];
  }
  __syncthreads();

  const int k   = tid >> 4;
  const int sub = tid & 15;
  float cr[NFFT], ci[NFFT];
#pragma unroll
  for (int n = 0; n < NFFT; ++n) { cr[n] = ctab[k*NFFT + n]; ci[n] = stab[k*NFFT + n]; }

  float* orow = out + (size_t)(r*BINS + k) * T_ + t0;
  const float inv_norm = 1.0f / 11.25f;

  for (int jj = 0; jj < 4; ++jj) {
    const int x0 = 4*sub + 64*jj;
    float smp[36];
#pragma unroll
    for (int q = 0; q < 9; ++q) {
      const float4 v = *(const float4*)&smem[x0 + 4*q];
      smp[4*q+0] = v.x; smp[4*q+1] = v.y; smp[4*q+2] = v.z; smp[4*q+3] = v.w;
    }
    float4 pw;
#pragma unroll
    for (int p = 0; p < 4; ++p) {
      float re = 0.f, im = 0.f;
#pragma unroll
      for (int n = 0; n < NFFT; ++n) {
        re += cr[n] * smp[p + n];
        im += ci[n] * smp[p + n];
      }
      ((float*)&pw)[p] = (re*re + im*im) * inv_norm;
    }
    *(float4*)(orow + x0) = pw;
  }
}

// ---------------- launch ----------------
extern "C" void kernel_launch(void* const* d_in, const int* in_sizes, int n_in,
                              void* d_out, int out_size, void* d_ws, size_t ws_size,
                              hipStream_t stream) {
  const float* x  = (const float*)d_in[0];
  const float* Wk = (const float*)d_in[1];
  const float* Wq = (const float*)d_in[2];
  const float* Wv = (const float*)d_in[3];
  float* out = (float*)d_out;
  float* ws  = (float*)d_ws;

  // gp: NP*1048576 halfs = NP*524288 float-slots. Then (floats):
  // wkg 65536, M 65536, seq 2097152, ctab 480, stab 480.
  const size_t tail = 65536ull*2 + 2097152ull + 960ull;
  const int np = (ws_size >= (16ull*524288ull + tail) * 4ull) ? 16 : 8;

  _Float16* gp = (_Float16*)ws;
  float* fbase = ws + (size_t)np*524288;
  float* wkg  = fbase;
  float* M    = fbase + 65536;
  float* seq  = M + 65536;
  float* ctab = seq + 2097152;
  float* stab = ctab + 480;

  spec_tables<<<1, 512, 0, stream>>>(ctab, stab);
  if (np == 16) {
    gram_mfma<16><<<dim3(2, 16, 16), 512, 0, stream>>>(x, gp);
    attn_a_t<16><<<dim3(8, 16), 256, 0, stream>>>(Wk, gp, wkg);
  } else {
    gram_mfma<8><<<dim3(2, 16, 8), 512, 0, stream>>>(x, gp);
    attn_a_t<8><<<dim3(8, 16), 256, 0, stream>>>(Wk, gp, wkg);
  }
  attn_b<<<dim3(16), 256, 0, stream>>>(Wq, Wv, wkg, M);
  outp_kernel<<<dim3(16, 16), 256, 0, stream>>>(x, M, seq);
  spec_kernel<<<dim3(32, 256), 256, 0, stream>>>(seq, ctab, stab, out);
}

// Round 10
// 232.418 us; speedup vs baseline: 1.2737x; 1.0088x over previous
//
#include <hip/hip_runtime.h>
#include <math.h>

#define B_   16
#define C_   256
#define T_   8192
#define BINS 16
#define NFFT 30

typedef __attribute__((ext_vector_type(8))) _Float16 f16x8;
typedef __attribute__((ext_vector_type(2))) __fp16 fp16x2;
typedef __attribute__((ext_vector_type(4))) float f32x4;

typedef const __attribute__((address_space(1))) unsigned int ga_u32;
typedef __attribute__((address_space(3))) unsigned int ls_u32;

union f16pack { f16x8 v; fp16x2 p[4]; };

// ---------------- Kernel 0: DFT coefficient tables (once) ----------------
__global__ __launch_bounds__(512) void spec_tables(float* __restrict__ ctab,
                                                   float* __restrict__ stab) {
  const int i = threadIdx.x;
  if (i < BINS*NFFT) {
    const int k = i / NFFT, n = i % NFFT;
    const float TWO_PI = 6.283185307179586f;
    const float wn = 0.5f - 0.5f * cosf(TWO_PI * (float)n / (float)NFFT);
    const float ang = TWO_PI * (float)(k * n) / (float)NFFT;
    ctab[i] = cosf(ang) * wn;
    stab[i] = sinf(ang) * wn;
  }
}

// ---------------- Kernel 1: k = Wk @ X  (fp16 out) ----------------
// R10: replaces the 256x256 Gram via associativity: scores use only
// Wk*G = (Wk X) X^T. One thread per (b,t); coalesced stride-T x reads;
// Wk rows via wave-uniform s_loads. Memory-bound on x (134 MB).
__global__ __launch_bounds__(256) void k_kernel(const float* __restrict__ x,
                                                const float* __restrict__ Wk,
                                                _Float16* __restrict__ kk) {
  const int tc = blockIdx.x;   // 0..31
  const int b  = blockIdx.y;
  const int tid = threadIdx.x;
  const int t = tc*256 + tid;
  const float* xb = x + (size_t)b*C_*T_ + t;
  float acc[16];
#pragma unroll
  for (int cc = 0; cc < 16; ++cc) acc[cc] = 0.f;
  for (int c4 = 0; c4 < 64; ++c4) {
    float xv[4];
#pragma unroll
    for (int j = 0; j < 4; ++j) xv[j] = xb[(size_t)(c4*4 + j)*T_];
#pragma unroll
    for (int cc = 0; cc < 16; ++cc) {
      const float4 w4 = *(const float4*)&Wk[cc*256 + c4*4];   // uniform -> s_load
      acc[cc] += w4.x*xv[0] + w4.y*xv[1] + w4.z*xv[2] + w4.w*xv[3];
    }
  }
#pragma unroll
  for (int cc = 0; cc < 16; ++cc)
    kk[((size_t)b*16 + cc)*T_ + t] = (_Float16)acc[cc];
}

// ---------------- Kernel 2: R partials = k @ X^T (MFMA, 32 K-splits) ----------------
static __device__ __forceinline__ void stage_panel(float* dstbase, const float* xb,
                                                   int koff, int tid) {
#pragma unroll
  for (int h = 0; h < 4; ++h) {
    const int idx = h*512 + tid;       // 0..2047 -> 2048 x 16B = 32 KB
    const int row = idx >> 3;          // 0..255
    const int ps  = idx & 7;           // physical 16B segment in row
    const int ls  = ps ^ (row & 7);    // logical segment (involution)
    const float* src = xb + (size_t)row*T_ + koff + ls*4;
    __builtin_amdgcn_global_load_lds((ga_u32*)src, (ls_u32*)(dstbase + idx*4), 16, 0, 0);
  }
}

__global__ __launch_bounds__(512, 4) void r_kernel(const float* __restrict__ x,
                                                   const _Float16* __restrict__ kk,
                                                   float* __restrict__ Rp) {
  const int ks = blockIdx.x;   // 0..31
  const int b  = blockIdx.y;
  constexpr int KCH = 256;

  __shared__ float P[2][256*32];

  const int tid  = threadIdx.x;
  const int lane = tid & 63;
  const int w    = tid >> 6;     // 0..7 -> ch-tile pair {2w, 2w+1}
  const int fr   = lane & 15;
  const int g    = lane >> 4;

  const float* xb = x + (size_t)b*C_*T_;
  const _Float16* kb = kk + (size_t)b*16*T_;
  const int t0 = ks * KCH;

  f32x4 acc[2];
  acc[0] = (f32x4){0.f,0.f,0.f,0.f};
  acc[1] = (f32x4){0.f,0.f,0.f,0.f};

  stage_panel(P[0], xb, t0, tid);
  __syncthreads();

  int cur = 0;
  for (int kt = 0; kt < KCH; kt += 32) {
    if (kt + 32 < KCH) stage_panel(P[cur ^ 1], xb, t0 + kt + 32, tid);

    const float* Pc = P[cur];
    // A-frag: k[cc=fr][t0+kt+g*8 .. +7], fp16 direct from L2
    const f16x8 ka = *(const f16x8*)&kb[(size_t)fr*T_ + t0 + kt + g*8];
#pragma unroll
    for (int nt = 0; nt < 2; ++nt) {
      const int r = (w*2 + nt)*16 + fr;   // ch row 0..255
      const float4 lo = *(const float4*)&Pc[r*32 + (((2*g+0) ^ (r&7))<<2)];
      const float4 hi = *(const float4*)&Pc[r*32 + (((2*g+1) ^ (r&7))<<2)];
      f16pack fb;
      fb.p[0] = __builtin_amdgcn_cvt_pkrtz(lo.x, lo.y);
      fb.p[1] = __builtin_amdgcn_cvt_pkrtz(lo.z, lo.w);
      fb.p[2] = __builtin_amdgcn_cvt_pkrtz(hi.x, hi.y);
      fb.p[3] = __builtin_amdgcn_cvt_pkrtz(hi.z, hi.w);
      acc[nt] = __builtin_amdgcn_mfma_f32_16x16x32_f16(ka, fb.v, acc[nt], 0, 0, 0);
    }
    __syncthreads();
    cur ^= 1;
  }

  float* rp = Rp + ((size_t)(ks*16 + b))*4096;
#pragma unroll
  for (int nt = 0; nt < 2; ++nt)
#pragma unroll
    for (int r = 0; r < 4; ++r) {
      const int cc = g*4 + r;               // C/D row = A-side m (cc)
      const int ch = (w*2 + nt)*16 + fr;    // C/D col = B-side n (ch)
      rp[cc*256 + ch] = acc[nt][r];
    }
}

// ---------------- Kernel 3: reduce Rp -> scores -> softmax -> M = P @ Wv ----------------
__global__ __launch_bounds__(256) void attn_b(const float* __restrict__ Wq,
                                              const float* __restrict__ Wv,
                                              const float* __restrict__ Rp,
                                              float* __restrict__ Mout) {
  const int b = blockIdx.x;
  const int tid = threadIdx.x;
  __shared__ float s1[16*256];
  __shared__ float s2[16*256];
  __shared__ float invs[16];

  // s1[cc][tid] = (WkG)[cc][tid] = sum over 32 K-split partials
#pragma unroll
  for (int cc = 0; cc < 16; ++cc) {
    float s = 0.f;
#pragma unroll 8
    for (int p = 0; p < 32; ++p)
      s += Rp[((size_t)(p*16 + b))*4096 + cc*256 + tid];
    s1[cc*256 + tid] = s;
  }
  __syncthreads();

  float sc[16];
#pragma unroll
  for (int cc = 0; cc < 16; ++cc) sc[cc] = 0.f;
  for (int c4 = 0; c4 < 64; ++c4) {
    const float4 wq4 = *(const float4*)&Wq[(size_t)tid*256 + c4*4];
#pragma unroll
    for (int cc = 0; cc < 16; ++cc) {
      const float4 p4 = *(const float4*)&s1[cc*256 + c4*4];
      sc[cc] += p4.x*wq4.x + p4.y*wq4.y + p4.z*wq4.z + p4.w*wq4.w;
    }
  }
#pragma unroll
  for (int cc = 0; cc < 16; ++cc) s2[cc*256 + tid] = sc[cc] * 0.0625f;
  __syncthreads();

  {
    const int rr = tid >> 4, jj = tid & 15;
    float mx = -1e30f;
    for (int c = jj; c < 256; c += 16) mx = fmaxf(mx, s2[rr*256 + c]);
    for (int o = 1; o < 16; o <<= 1) mx = fmaxf(mx, __shfl_xor(mx, o, 64));
    float sm = 0.f;
    for (int c = jj; c < 256; c += 16) {
      const float e = __expf(s2[rr*256 + c] - mx);
      s2[rr*256 + c] = e;
      sm += e;
    }
    for (int o = 1; o < 16; o <<= 1) sm += __shfl_xor(sm, o, 64);
    if (jj == 0) invs[rr] = 1.f / sm;
  }
  __syncthreads();

  float mac[16];
#pragma unroll
  for (int cc = 0; cc < 16; ++cc) mac[cc] = 0.f;
  for (int c4 = 0; c4 < 64; ++c4) {
    float wv[4];
#pragma unroll
    for (int j = 0; j < 4; ++j) wv[j] = Wv[(size_t)(c4*4 + j)*256 + tid];
#pragma unroll
    for (int cc = 0; cc < 16; ++cc) {
      const float4 p4 = *(const float4*)&s2[cc*256 + c4*4];
      mac[cc] += p4.x*wv[0] + p4.y*wv[1] + p4.z*wv[2] + p4.w*wv[3];
    }
  }
#pragma unroll
  for (int cc = 0; cc < 16; ++cc)
    Mout[(size_t)b*4096 + cc*256 + tid] = mac[cc] * invs[cc];
}

// ---------------- Kernel 4: seq = M @ X  (256 blocks, float2) ----------------
__global__ __launch_bounds__(256) void outp_kernel(const float* __restrict__ x,
                                                   const float* __restrict__ M,
                                                   float* __restrict__ seq) {
  const int tc = blockIdx.x;   // 0..15
  const int b  = blockIdx.y;
  const int tid = threadIdx.x;
  const int t  = tc*512 + tid*2;
  const float* xb = x + (size_t)b*C_*T_ + t;
  const float* mb = M + (size_t)b*4096;
  float2 a[16];
#pragma unroll
  for (int cc = 0; cc < 16; ++cc) a[cc] = make_float2(0.f, 0.f);
  for (int ch = 0; ch < 64; ++ch) {
    float2 xv[4];
#pragma unroll
    for (int j = 0; j < 4; ++j)
      xv[j] = *(const float2*)(xb + (size_t)(ch*4 + j) * T_);
#pragma unroll
    for (int cc = 0; cc < 16; ++cc) {
      const float4 m4 = *(const float4*)(mb + cc*256 + ch*4);
      a[cc].x += m4.x*xv[0].x + m4.y*xv[1].x + m4.z*xv[2].x + m4.w*xv[3].x;
      a[cc].y += m4.x*xv[0].y + m4.y*xv[1].y + m4.z*xv[2].y + m4.w*xv[3].y;
    }
  }
#pragma unroll
  for (int cc = 0; cc < 16; ++cc)
    *(float2*)(seq + (size_t)(b*16 + cc)*T_ + t) = a[cc];
}

// ---------------- Kernel 5: windowed-DFT power spectrogram ----------------
__global__ __launch_bounds__(256) void spec_kernel(const float* __restrict__ seq,
                                                   const float* __restrict__ ctabg,
                                                   const float* __restrict__ stabg,
                                                   float* __restrict__ out) {
  const int tcx = blockIdx.x;  // 0..31
  const int r   = blockIdx.y;  // 0..255
  const int tid = threadIdx.x;
  const int t0  = tcx * 256;

  __shared__ float smem[288];
  __shared__ float ctab[BINS*NFFT];
  __shared__ float stab[BINS*NFFT];

  const float* row = seq + (size_t)r * T_;
  for (int i = tid; i < 288; i += 256) {
    int gg = t0 - 15 + i;
    if (gg < 0) gg = -gg;
    if (gg > T_-1) gg = 2*(T_-1) - gg;
    smem[i] = row[gg];
  }
  for (int i = tid; i < BINS*NFFT; i += 256) {
    ctab[i] = ctabg[i];
    stab[i] = stabg[i];
  }
  __syncthreads();

  const int k   = tid >> 4;
  const int sub = tid & 15;
  float cr[NFFT], ci[NFFT];
#pragma unroll
  for (int n = 0; n < NFFT; ++n) { cr[n] = ctab[k*NFFT + n]; ci[n] = stab[k*NFFT + n]; }

  float* orow = out + (size_t)(r*BINS + k) * T_ + t0;
  const float inv_norm = 1.0f / 11.25f;

  for (int jj = 0; jj < 4; ++jj) {
    const int x0 = 4*sub + 64*jj;
    float smp[36];
#pragma unroll
    for (int q = 0; q < 9; ++q) {
      const float4 v = *(const float4*)&smem[x0 + 4*q];
      smp[4*q+0] = v.x; smp[4*q+1] = v.y; smp[4*q+2] = v.z; smp[4*q+3] = v.w;
    }
    float4 pw;
#pragma unroll
    for (int p = 0; p < 4; ++p) {
      float re = 0.f, im = 0.f;
#pragma unroll
      for (int n = 0; n < NFFT; ++n) {
        re += cr[n] * smp[p + n];
        im += ci[n] * smp[p + n];
      }
      ((float*)&pw)[p] = (re*re + im*im) * inv_norm;
    }
    *(float4*)(orow + x0) = pw;
  }
}

// ---------------- launch ----------------
extern "C" void kernel_launch(void* const* d_in, const int* in_sizes, int n_in,
                              void* d_out, int out_size, void* d_ws, size_t ws_size,
                              hipStream_t stream) {
  const float* x  = (const float*)d_in[0];
  const float* Wk = (const float*)d_in[1];
  const float* Wq = (const float*)d_in[2];
  const float* Wv = (const float*)d_in[3];
  float* out = (float*)d_out;
  float* ws  = (float*)d_ws;

  // float-slot layout (total ~5.3M floats = 21 MB):
  _Float16* kk = (_Float16*)ws;            // 16*16*8192 halfs = 1,048,576 slots
  float* Rp   = ws + 1048576;              // 32*16*16*256 = 2,097,152
  float* M    = Rp + 2097152;              // 65,536
  float* seq  = M + 65536;                 // 2,097,152
  float* ctab = seq + 2097152;             // 480
  float* stab = ctab + 480;                // 480

  spec_tables<<<1, 512, 0, stream>>>(ctab, stab);
  k_kernel<<<dim3(32, 16), 256, 0, stream>>>(x, Wk, kk);
  r_kernel<<<dim3(32, 16), 512, 0, stream>>>(x, kk, Rp);
  attn_b<<<dim3(16), 256, 0, stream>>>(Wq, Wv, Rp, M);
  outp_kernel<<<dim3(16, 16), 256, 0, stream>>>(x, M, seq);
  spec_kernel<<<dim3(32, 256), 256, 0, stream>>>(seq, ctab, stab, out);
}

// Round 11
// 216.349 us; speedup vs baseline: 1.3683x; 1.0743x over previous
//
#include <hip/hip_runtime.h>
#include <math.h>

#define B_   16
#define C_   256
#define T_   8192
#define BINS 16
#define NFFT 30

typedef __attribute__((ext_vector_type(8))) _Float16 f16x8;
typedef __attribute__((ext_vector_type(2))) __fp16 fp16x2;
typedef __attribute__((ext_vector_type(4))) float f32x4;

typedef const __attribute__((address_space(1))) unsigned int ga_u32;
typedef __attribute__((address_space(3))) unsigned int ls_u32;

union f16pack { f16x8 v; fp16x2 p[4]; };

// ---------------- Kernel 0: DFT coefficient tables (once) ----------------
__global__ __launch_bounds__(512) void spec_tables(float* __restrict__ ctab,
                                                   float* __restrict__ stab) {
  const int i = threadIdx.x;
  if (i < BINS*NFFT) {
    const int k = i / NFFT, n = i % NFFT;
    const float TWO_PI = 6.283185307179586f;
    const float wn = 0.5f - 0.5f * cosf(TWO_PI * (float)n / (float)NFFT);
    const float ang = TWO_PI * (float)(k * n) / (float)NFFT;
    ctab[i] = cosf(ang) * wn;
    stab[i] = sinf(ang) * wn;
  }
}

// ---------------- Kernel 1: k = Wk @ X  (fp16 out) ----------------
__global__ __launch_bounds__(256) void k_kernel(const float* __restrict__ x,
                                                const float* __restrict__ Wk,
                                                _Float16* __restrict__ kk) {
  const int tc = blockIdx.x;   // 0..31
  const int b  = blockIdx.y;
  const int tid = threadIdx.x;
  const int t = tc*256 + tid;
  const float* xb = x + (size_t)b*C_*T_ + t;
  float acc[16];
#pragma unroll
  for (int cc = 0; cc < 16; ++cc) acc[cc] = 0.f;
  for (int c4 = 0; c4 < 64; ++c4) {
    float xv[4];
#pragma unroll
    for (int j = 0; j < 4; ++j) xv[j] = xb[(size_t)(c4*4 + j)*T_];
#pragma unroll
    for (int cc = 0; cc < 16; ++cc) {
      const float4 w4 = *(const float4*)&Wk[cc*256 + c4*4];   // uniform -> s_load
      acc[cc] += w4.x*xv[0] + w4.y*xv[1] + w4.z*xv[2] + w4.w*xv[3];
    }
  }
#pragma unroll
  for (int cc = 0; cc < 16; ++cc)
    kk[((size_t)b*16 + cc)*T_ + t] = (_Float16)acc[cc];
}

// ---------------- Kernel 2: R partials = k @ X^T (MFMA, 32 K-splits) ----------------
static __device__ __forceinline__ void stage_panel(float* dstbase, const float* xb,
                                                   int koff, int tid) {
#pragma unroll
  for (int h = 0; h < 4; ++h) {
    const int idx = h*512 + tid;       // 0..2047 -> 2048 x 16B = 32 KB
    const int row = idx >> 3;          // 0..255
    const int ps  = idx & 7;           // physical 16B segment in row
    const int ls  = ps ^ (row & 7);    // logical segment (involution)
    const float* src = xb + (size_t)row*T_ + koff + ls*4;
    __builtin_amdgcn_global_load_lds((ga_u32*)src, (ls_u32*)(dstbase + idx*4), 16, 0, 0);
  }
}

__global__ __launch_bounds__(512, 4) void r_kernel(const float* __restrict__ x,
                                                   const _Float16* __restrict__ kk,
                                                   float* __restrict__ Rp) {
  const int ks = blockIdx.x;   // 0..31
  const int b  = blockIdx.y;
  constexpr int KCH = 256;

  __shared__ float P[2][256*32];

  const int tid  = threadIdx.x;
  const int lane = tid & 63;
  const int w    = tid >> 6;     // 0..7 -> ch-tile pair {2w, 2w+1}
  const int fr   = lane & 15;
  const int g    = lane >> 4;

  const float* xb = x + (size_t)b*C_*T_;
  const _Float16* kb = kk + (size_t)b*16*T_;
  const int t0 = ks * KCH;

  f32x4 acc[2];
  acc[0] = (f32x4){0.f,0.f,0.f,0.f};
  acc[1] = (f32x4){0.f,0.f,0.f,0.f};

  stage_panel(P[0], xb, t0, tid);
  __syncthreads();

  int cur = 0;
  for (int kt = 0; kt < KCH; kt += 32) {
    if (kt + 32 < KCH) stage_panel(P[cur ^ 1], xb, t0 + kt + 32, tid);

    const float* Pc = P[cur];
    const f16x8 ka = *(const f16x8*)&kb[(size_t)fr*T_ + t0 + kt + g*8];
#pragma unroll
    for (int nt = 0; nt < 2; ++nt) {
      const int r = (w*2 + nt)*16 + fr;   // ch row 0..255
      const float4 lo = *(const float4*)&Pc[r*32 + (((2*g+0) ^ (r&7))<<2)];
      const float4 hi = *(const float4*)&Pc[r*32 + (((2*g+1) ^ (r&7))<<2)];
      f16pack fb;
      fb.p[0] = __builtin_amdgcn_cvt_pkrtz(lo.x, lo.y);
      fb.p[1] = __builtin_amdgcn_cvt_pkrtz(lo.z, lo.w);
      fb.p[2] = __builtin_amdgcn_cvt_pkrtz(hi.x, hi.y);
      fb.p[3] = __builtin_amdgcn_cvt_pkrtz(hi.z, hi.w);
      acc[nt] = __builtin_amdgcn_mfma_f32_16x16x32_f16(ka, fb.v, acc[nt], 0, 0, 0);
    }
    __syncthreads();
    cur ^= 1;
  }

  float* rp = Rp + ((size_t)(ks*16 + b))*4096;
#pragma unroll
  for (int nt = 0; nt < 2; ++nt)
#pragma unroll
    for (int r = 0; r < 4; ++r) {
      const int cc = g*4 + r;               // C/D row = A-side m (cc)
      const int ch = (w*2 + nt)*16 + fr;    // C/D col = B-side n (ch)
      rp[cc*256 + ch] = acc[nt][r];
    }
}

// ---------------- Kernel 2b: parallel reduce of 32 Rp partials -> wkg ----------------
// 65536 outputs; thread idx -> (b = idx>>12, rem = idx&4095); coalesced.
__global__ __launch_bounds__(256) void reduce_kernel(const float* __restrict__ Rp,
                                                     float* __restrict__ wkg) {
  const int idx = blockIdx.x*256 + threadIdx.x;   // 0..65535
  const int b   = idx >> 12;
  const int rem = idx & 4095;
  float s = 0.f;
#pragma unroll 8
  for (int p = 0; p < 32; ++p)
    s += Rp[((size_t)(p*16 + b))*4096 + rem];
  wkg[idx] = s;
}

// ---------------- Kernel 3: scores -> softmax -> M = P @ Wv ----------------
__global__ __launch_bounds__(256) void attn_b(const float* __restrict__ Wq,
                                              const float* __restrict__ Wv,
                                              const float* __restrict__ wkg,
                                              float* __restrict__ Mout) {
  const int b = blockIdx.x;
  const int tid = threadIdx.x;
  __shared__ float s1[16*256];
  __shared__ float s2[16*256];
  __shared__ float invs[16];

#pragma unroll
  for (int cc = 0; cc < 16; ++cc) s1[cc*256 + tid] = wkg[(size_t)b*4096 + cc*256 + tid];
  __syncthreads();

  float sc[16];
#pragma unroll
  for (int cc = 0; cc < 16; ++cc) sc[cc] = 0.f;
  for (int c4 = 0; c4 < 64; ++c4) {
    const float4 wq4 = *(const float4*)&Wq[(size_t)tid*256 + c4*4];
#pragma unroll
    for (int cc = 0; cc < 16; ++cc) {
      const float4 p4 = *(const float4*)&s1[cc*256 + c4*4];
      sc[cc] += p4.x*wq4.x + p4.y*wq4.y + p4.z*wq4.z + p4.w*wq4.w;
    }
  }
#pragma unroll
  for (int cc = 0; cc < 16; ++cc) s2[cc*256 + tid] = sc[cc] * 0.0625f;
  __syncthreads();

  {
    const int rr = tid >> 4, jj = tid & 15;
    float mx = -1e30f;
    for (int c = jj; c < 256; c += 16) mx = fmaxf(mx, s2[rr*256 + c]);
    for (int o = 1; o < 16; o <<= 1) mx = fmaxf(mx, __shfl_xor(mx, o, 64));
    float sm = 0.f;
    for (int c = jj; c < 256; c += 16) {
      const float e = __expf(s2[rr*256 + c] - mx);
      s2[rr*256 + c] = e;
      sm += e;
    }
    for (int o = 1; o < 16; o <<= 1) sm += __shfl_xor(sm, o, 64);
    if (jj == 0) invs[rr] = 1.f / sm;
  }
  __syncthreads();

  float mac[16];
#pragma unroll
  for (int cc = 0; cc < 16; ++cc) mac[cc] = 0.f;
  for (int c4 = 0; c4 < 64; ++c4) {
    float wv[4];
#pragma unroll
    for (int j = 0; j < 4; ++j) wv[j] = Wv[(size_t)(c4*4 + j)*256 + tid];
#pragma unroll
    for (int cc = 0; cc < 16; ++cc) {
      const float4 p4 = *(const float4*)&s2[cc*256 + c4*4];
      mac[cc] += p4.x*wv[0] + p4.y*wv[1] + p4.z*wv[2] + p4.w*wv[3];
    }
  }
#pragma unroll
  for (int cc = 0; cc < 16; ++cc)
    Mout[(size_t)b*4096 + cc*256 + tid] = mac[cc] * invs[cc];
}

// ---------------- Kernel 4: seq = M @ X  (256 blocks, float2) ----------------
__global__ __launch_bounds__(256) void outp_kernel(const float* __restrict__ x,
                                                   const float* __restrict__ M,
                                                   float* __restrict__ seq) {
  const int tc = blockIdx.x;   // 0..15
  const int b  = blockIdx.y;
  const int tid = threadIdx.x;
  const int t  = tc*512 + tid*2;
  const float* xb = x + (size_t)b*C_*T_ + t;
  const float* mb = M + (size_t)b*4096;
  float2 a[16];
#pragma unroll
  for (int cc = 0; cc < 16; ++cc) a[cc] = make_float2(0.f, 0.f);
  for (int ch = 0; ch < 64; ++ch) {
    float2 xv[4];
#pragma unroll
    for (int j = 0; j < 4; ++j)
      xv[j] = *(const float2*)(xb + (size_t)(ch*4 + j) * T_);
#pragma unroll
    for (int cc = 0; cc < 16; ++cc) {
      const float4 m4 = *(const float4*)(mb + cc*256 + ch*4);
      a[cc].x += m4.x*xv[0].x + m4.y*xv[1].x + m4.z*xv[2].x + m4.w*xv[3].x;
      a[cc].y += m4.x*xv[0].y + m4.y*xv[1].y + m4.z*xv[2].y + m4.w*xv[3].y;
    }
  }
#pragma unroll
  for (int cc = 0; cc < 16; ++cc)
    *(float2*)(seq + (size_t)(b*16 + cc)*T_ + t) = a[cc];
}

// ---------------- Kernel 5: windowed-DFT power spectrogram ----------------
__global__ __launch_bounds__(256) void spec_kernel(const float* __restrict__ seq,
                                                   const float* __restrict__ ctabg,
                                                   const float* __restrict__ stabg,
                                                   float* __restrict__ out) {
  const int tcx = blockIdx.x;  // 0..31
  const int r   = blockIdx.y;  // 0..255
  const int tid = threadIdx.x;
  const int t0  = tcx * 256;

  __shared__ float smem[288];
  __shared__ float ctab[BINS*NFFT];
  __shared__ float stab[BINS*NFFT];

  const float* row = seq + (size_t)r * T_;
  for (int i = tid; i < 288; i += 256) {
    int gg = t0 - 15 + i;
    if (gg < 0) gg = -gg;
    if (gg > T_-1) gg = 2*(T_-1) - gg;
    smem[i] = row[gg];
  }
  for (int i = tid; i < BINS*NFFT; i += 256) {
    ctab[i] = ctabg[i];
    stab[i] = stabg[i];
  }
  __syncthreads();

  const int k   = tid >> 4;
  const int sub = tid & 15;
  float cr[NFFT], ci[NFFT];
#pragma unroll
  for (int n = 0; n < NFFT; ++n) { cr[n] = ctab[k*NFFT + n]; ci[n] = stab[k*NFFT + n]; }

  float* orow = out + (size_t)(r*BINS + k) * T_ + t0;
  const float inv_norm = 1.0f / 11.25f;

  for (int jj = 0; jj < 4; ++jj) {
    const int x0 = 4*sub + 64*jj;
    float smp[36];
#pragma unroll
    for (int q = 0; q < 9; ++q) {
      const float4 v = *(const float4*)&smem[x0 + 4*q];
      smp[4*q+0] = v.x; smp[4*q+1] = v.y; smp[4*q+2] = v.z; smp[4*q+3] = v.w;
    }
    float4 pw;
#pragma unroll
    for (int p = 0; p < 4; ++p) {
      float re = 0.f, im = 0.f;
#pragma unroll
      for (int n = 0; n < NFFT; ++n) {
        re += cr[n] * smp[p + n];
        im += ci[n] * smp[p + n];
      }
      ((float*)&pw)[p] = (re*re + im*im) * inv_norm;
    }
    *(float4*)(orow + x0) = pw;
  }
}

// ---------------- launch ----------------
extern "C" void kernel_launch(void* const* d_in, const int* in_sizes, int n_in,
                              void* d_out, int out_size, void* d_ws, size_t ws_size,
                              hipStream_t stream) {
  const float* x  = (const float*)d_in[0];
  const float* Wk = (const float*)d_in[1];
  const float* Wq = (const float*)d_in[2];
  const float* Wv = (const float*)d_in[3];
  float* out = (float*)d_out;
  float* ws  = (float*)d_ws;

  // float-slot layout (total ~5.4M floats = 21.5 MB):
  _Float16* kk = (_Float16*)ws;            // 16*16*8192 halfs = 1,048,576 slots
  float* Rp   = ws + 1048576;              // 32*16*16*256 = 2,097,152
  float* wkg  = Rp + 2097152;              // 65,536
  float* M    = wkg + 65536;               // 65,536
  float* seq  = M + 65536;                 // 2,097,152
  float* ctab = seq + 2097152;             // 480
  float* stab = ctab + 480;                // 480

  spec_tables<<<1, 512, 0, stream>>>(ctab, stab);
  k_kernel<<<dim3(32, 16), 256, 0, stream>>>(x, Wk, kk);
  r_kernel<<<dim3(32, 16), 512, 0, stream>>>(x, kk, Rp);
  reduce_kernel<<<dim3(256), 256, 0, stream>>>(Rp, wkg);
  attn_b<<<dim3(16), 256, 0, stream>>>(Wq, Wv, wkg, M);
  outp_kernel<<<dim3(16, 16), 256, 0, stream>>>(x, M, seq);
  spec_kernel<<<dim3(32, 256), 256, 0, stream>>>(seq, ctab, stab, out);
}

// Round 12
// 214.005 us; speedup vs baseline: 1.3833x; 1.0110x over previous
//
#include <hip/hip_runtime.h>
#include <math.h>

#define B_   16
#define C_   256
#define T_   8192
#define BINS 16
#define NFFT 30

typedef __attribute__((ext_vector_type(8))) _Float16 f16x8;
typedef __attribute__((ext_vector_type(2))) __fp16 fp16x2;
typedef __attribute__((ext_vector_type(4))) float f32x4;

typedef const __attribute__((address_space(1))) unsigned int ga_u32;
typedef __attribute__((address_space(3))) unsigned int ls_u32;

union f16pack { f16x8 v; fp16x2 p[4]; };

// ---------------- Kernel 1: k = Wk @ X  (fp16 out, float2 per thread) ----------------
__global__ __launch_bounds__(256) void k_kernel(const float* __restrict__ x,
                                                const float* __restrict__ Wk,
                                                _Float16* __restrict__ kk) {
  const int tc = blockIdx.x;   // 0..15
  const int b  = blockIdx.y;
  const int tid = threadIdx.x;
  const int t = tc*512 + tid*2;
  const float* xb = x + (size_t)b*C_*T_ + t;
  float2 acc[16];
#pragma unroll
  for (int cc = 0; cc < 16; ++cc) acc[cc] = make_float2(0.f, 0.f);
  for (int c4 = 0; c4 < 64; ++c4) {
    float2 xv[4];
#pragma unroll
    for (int j = 0; j < 4; ++j) xv[j] = *(const float2*)(xb + (size_t)(c4*4 + j)*T_);
#pragma unroll
    for (int cc = 0; cc < 16; ++cc) {
      const float4 w4 = *(const float4*)&Wk[cc*256 + c4*4];   // uniform -> s_load
      acc[cc].x += w4.x*xv[0].x + w4.y*xv[1].x + w4.z*xv[2].x + w4.w*xv[3].x;
      acc[cc].y += w4.x*xv[0].y + w4.y*xv[1].y + w4.z*xv[2].y + w4.w*xv[3].y;
    }
  }
#pragma unroll
  for (int cc = 0; cc < 16; ++cc) {
    fp16x2 hv;
    hv[0] = (__fp16)acc[cc].x;
    hv[1] = (__fp16)acc[cc].y;
    *(fp16x2*)&kk[((size_t)b*16 + cc)*T_ + t] = hv;
  }
}

// ---------------- Kernel 2: R partials = k @ X^T (MFMA, 32 K-splits) ----------------
static __device__ __forceinline__ void stage_panel(float* dstbase, const float* xb,
                                                   int koff, int tid) {
#pragma unroll
  for (int h = 0; h < 4; ++h) {
    const int idx = h*512 + tid;       // 0..2047 -> 2048 x 16B = 32 KB
    const int row = idx >> 3;          // 0..255
    const int ps  = idx & 7;           // physical 16B segment in row
    const int ls  = ps ^ (row & 7);    // logical segment (involution)
    const float* src = xb + (size_t)row*T_ + koff + ls*4;
    __builtin_amdgcn_global_load_lds((ga_u32*)src, (ls_u32*)(dstbase + idx*4), 16, 0, 0);
  }
}

__global__ __launch_bounds__(512, 4) void r_kernel(const float* __restrict__ x,
                                                   const _Float16* __restrict__ kk,
                                                   float* __restrict__ Rp) {
  const int ks = blockIdx.x;   // 0..31
  const int b  = blockIdx.y;
  constexpr int KCH = 256;

  __shared__ float P[2][256*32];

  const int tid  = threadIdx.x;
  const int lane = tid & 63;
  const int w    = tid >> 6;     // 0..7 -> ch-tile pair {2w, 2w+1}
  const int fr   = lane & 15;
  const int g    = lane >> 4;

  const float* xb = x + (size_t)b*C_*T_;
  const _Float16* kb = kk + (size_t)b*16*T_;
  const int t0 = ks * KCH;

  f32x4 acc[2];
  acc[0] = (f32x4){0.f,0.f,0.f,0.f};
  acc[1] = (f32x4){0.f,0.f,0.f,0.f};

  stage_panel(P[0], xb, t0, tid);
  __syncthreads();

  int cur = 0;
  for (int kt = 0; kt < KCH; kt += 32) {
    if (kt + 32 < KCH) stage_panel(P[cur ^ 1], xb, t0 + kt + 32, tid);

    const float* Pc = P[cur];
    const f16x8 ka = *(const f16x8*)&kb[(size_t)fr*T_ + t0 + kt + g*8];
#pragma unroll
    for (int nt = 0; nt < 2; ++nt) {
      const int r = (w*2 + nt)*16 + fr;   // ch row 0..255
      const float4 lo = *(const float4*)&Pc[r*32 + (((2*g+0) ^ (r&7))<<2)];
      const float4 hi = *(const float4*)&Pc[r*32 + (((2*g+1) ^ (r&7))<<2)];
      f16pack fb;
      fb.p[0] = __builtin_amdgcn_cvt_pkrtz(lo.x, lo.y);
      fb.p[1] = __builtin_amdgcn_cvt_pkrtz(lo.z, lo.w);
      fb.p[2] = __builtin_amdgcn_cvt_pkrtz(hi.x, hi.y);
      fb.p[3] = __builtin_amdgcn_cvt_pkrtz(hi.z, hi.w);
      acc[nt] = __builtin_amdgcn_mfma_f32_16x16x32_f16(ka, fb.v, acc[nt], 0, 0, 0);
    }
    __syncthreads();
    cur ^= 1;
  }

  float* rp = Rp + ((size_t)(ks*16 + b))*4096;
#pragma unroll
  for (int nt = 0; nt < 2; ++nt)
#pragma unroll
    for (int r = 0; r < 4; ++r) {
      const int cc = g*4 + r;               // C/D row = A-side m (cc)
      const int ch = (w*2 + nt)*16 + fr;    // C/D col = B-side n (ch)
      rp[cc*256 + ch] = acc[nt][r];
    }
}

// ---------------- Kernel 2b: parallel reduce of 32 Rp partials -> wkg ----------------
__global__ __launch_bounds__(256) void reduce_kernel(const float* __restrict__ Rp,
                                                     float* __restrict__ wkg) {
  const int idx = blockIdx.x*256 + threadIdx.x;   // 0..65535
  const int b   = idx >> 12;
  const int rem = idx & 4095;
  float s = 0.f;
#pragma unroll 8
  for (int p = 0; p < 32; ++p)
    s += Rp[((size_t)(p*16 + b))*4096 + rem];
  wkg[idx] = s;
}

// ---------------- Kernel 3: scores -> softmax -> M = P @ Wv (512 thr) ----------------
__global__ __launch_bounds__(512) void attn_b(const float* __restrict__ Wq,
                                              const float* __restrict__ Wv,
                                              const float* __restrict__ wkg,
                                              float* __restrict__ Mout) {
  const int b = blockIdx.x;
  const int tid = threadIdx.x;
  __shared__ float s1[16*256];
  __shared__ float s2[16*256];
  __shared__ float invs[16];

  for (int i = tid; i < 4096; i += 512) s1[i] = wkg[(size_t)b*4096 + i];
  __syncthreads();

  const int h   = tid >> 8;    // 0..1 (cc half)
  const int col = tid & 255;

  float sc[8];
#pragma unroll
  for (int i = 0; i < 8; ++i) sc[i] = 0.f;
  for (int c4 = 0; c4 < 64; ++c4) {
    const float4 wq4 = *(const float4*)&Wq[(size_t)col*256 + c4*4];
#pragma unroll
    for (int i = 0; i < 8; ++i) {
      const float4 p4 = *(const float4*)&s1[(h*8 + i)*256 + c4*4];
      sc[i] += p4.x*wq4.x + p4.y*wq4.y + p4.z*wq4.z + p4.w*wq4.w;
    }
  }
#pragma unroll
  for (int i = 0; i < 8; ++i) s2[(h*8 + i)*256 + col] = sc[i] * 0.0625f;
  __syncthreads();

  // softmax: 16 rows x 32 lanes (shfl stays within 32-lane half)
  {
    const int rr = tid >> 5, jj = tid & 31;
    float mx = -1e30f;
    for (int c = jj; c < 256; c += 32) mx = fmaxf(mx, s2[rr*256 + c]);
#pragma unroll
    for (int o = 1; o < 32; o <<= 1) mx = fmaxf(mx, __shfl_xor(mx, o, 64));
    float sm = 0.f;
    for (int c = jj; c < 256; c += 32) {
      const float e = __expf(s2[rr*256 + c] - mx);
      s2[rr*256 + c] = e;
      sm += e;
    }
#pragma unroll
    for (int o = 1; o < 32; o <<= 1) sm += __shfl_xor(sm, o, 64);
    if (jj == 0) invs[rr] = 1.f / sm;
  }
  __syncthreads();

  float mac[8];
#pragma unroll
  for (int i = 0; i < 8; ++i) mac[i] = 0.f;
  for (int c4 = 0; c4 < 64; ++c4) {
    float wv[4];
#pragma unroll
    for (int j = 0; j < 4; ++j) wv[j] = Wv[(size_t)(c4*4 + j)*256 + col];
#pragma unroll
    for (int i = 0; i < 8; ++i) {
      const float4 p4 = *(const float4*)&s2[(h*8 + i)*256 + c4*4];
      mac[i] += p4.x*wv[0] + p4.y*wv[1] + p4.z*wv[2] + p4.w*wv[3];
    }
  }
#pragma unroll
  for (int i = 0; i < 8; ++i)
    Mout[(size_t)b*4096 + (h*8 + i)*256 + col] = mac[i] * invs[h*8 + i];
}

// ---------------- Kernel 4: seq = M @ X  (256 blocks, float2) ----------------
__global__ __launch_bounds__(256) void outp_kernel(const float* __restrict__ x,
                                                   const float* __restrict__ M,
                                                   float* __restrict__ seq) {
  const int tc = blockIdx.x;   // 0..15
  const int b  = blockIdx.y;
  const int tid = threadIdx.x;
  const int t  = tc*512 + tid*2;
  const float* xb = x + (size_t)b*C_*T_ + t;
  const float* mb = M + (size_t)b*4096;
  float2 a[16];
#pragma unroll
  for (int cc = 0; cc < 16; ++cc) a[cc] = make_float2(0.f, 0.f);
  for (int ch = 0; ch < 64; ++ch) {
    float2 xv[4];
#pragma unroll
    for (int j = 0; j < 4; ++j)
      xv[j] = *(const float2*)(xb + (size_t)(ch*4 + j) * T_);
#pragma unroll
    for (int cc = 0; cc < 16; ++cc) {
      const float4 m4 = *(const float4*)(mb + cc*256 + ch*4);
      a[cc].x += m4.x*xv[0].x + m4.y*xv[1].x + m4.z*xv[2].x + m4.w*xv[3].x;
      a[cc].y += m4.x*xv[0].y + m4.y*xv[1].y + m4.z*xv[2].y + m4.w*xv[3].y;
    }
  }
#pragma unroll
  for (int cc = 0; cc < 16; ++cc)
    *(float2*)(seq + (size_t)(b*16 + cc)*T_ + t) = a[cc];
}

// ---------------- Kernel 5: windowed-DFT power spectrogram ----------------
__global__ __launch_bounds__(256) void spec_kernel(const float* __restrict__ seq,
                                                   float* __restrict__ out) {
  const int tcx = blockIdx.x;  // 0..31
  const int r   = blockIdx.y;  // 0..255
  const int tid = threadIdx.x;
  const int t0  = tcx * 256;

  __shared__ float smem[288];
  __shared__ float ctab[BINS*NFFT];
  __shared__ float stab[BINS*NFFT];

  const float* row = seq + (size_t)r * T_;
  for (int i = tid; i < 288; i += 256) {
    int gg = t0 - 15 + i;
    if (gg < 0) gg = -gg;
    if (gg > T_-1) gg = 2*(T_-1) - gg;
    smem[i] = row[gg];
  }
  for (int i = tid; i < BINS*NFFT; i += 256) {
    const int k = i / NFFT, n = i % NFFT;
    const float TWO_PI = 6.283185307179586f;
    const float wn = 0.5f - 0.5f * cosf(TWO_PI * (float)n / (float)NFFT);
    const float ang = TWO_PI * (float)(k * n) / (float)NFFT;
    ctab[i] = cosf(ang) * wn;
    stab[i] = sinf(ang) * wn;
  }
  __syncthreads();

  const int k   = tid >> 4;
  const int sub = tid & 15;
  float cr[NFFT], ci[NFFT];
#pragma unroll
  for (int n = 0; n < NFFT; ++n) { cr[n] = ctab[k*NFFT + n]; ci[n] = stab[k*NFFT + n]; }

  float* orow = out + (size_t)(r*BINS + k) * T_ + t0;
  const float inv_norm = 1.0f / 11.25f;

  for (int jj = 0; jj < 4; ++jj) {
    const int x0 = 4*sub + 64*jj;
    float smp[36];
#pragma unroll
    for (int q = 0; q < 9; ++q) {
      const float4 v = *(const float4*)&smem[x0 + 4*q];
      smp[4*q+0] = v.x; smp[4*q+1] = v.y; smp[4*q+2] = v.z; smp[4*q+3] = v.w;
    }
    float4 pw;
#pragma unroll
    for (int p = 0; p < 4; ++p) {
      float re = 0.f, im = 0.f;
#pragma unroll
      for (int n = 0; n < NFFT; ++n) {
        re += cr[n] * smp[p + n];
        im += ci[n] * smp[p + n];
      }
      ((float*)&pw)[p] = (re*re + im*im) * inv_norm;
    }
    *(float4*)(orow + x0) = pw;
  }
}

// ---------------- launch ----------------
extern "C" void kernel_launch(void* const* d_in, const int* in_sizes, int n_in,
                              void* d_out, int out_size, void* d_ws, size_t ws_size,
                              hipStream_t stream) {
  const float* x  = (const float*)d_in[0];
  const float* Wk = (const float*)d_in[1];
  const float* Wq = (const float*)d_in[2];
  const float* Wv = (const float*)d_in[3];
  float* out = (float*)d_out;
  float* ws  = (float*)d_ws;

  // float-slot layout (total ~5.4M floats = 21.5 MB):
  _Float16* kk = (_Float16*)ws;            // 16*16*8192 halfs = 1,048,576 slots
  float* Rp   = ws + 1048576;              // 32*16*16*256 = 2,097,152
  float* wkg  = Rp + 2097152;              // 65,536
  float* M    = wkg + 65536;               // 65,536
  float* seq  = M + 65536;                 // 2,097,152

  k_kernel<<<dim3(16, 16), 256, 0, stream>>>(x, Wk, kk);
  r_kernel<<<dim3(32, 16), 512, 0, stream>>>(x, kk, Rp);
  reduce_kernel<<<dim3(256), 256, 0, stream>>>(Rp, wkg);
  attn_b<<<dim3(16), 512, 0, stream>>>(Wq, Wv, wkg, M);
  outp_kernel<<<dim3(16, 16), 256, 0, stream>>>(x, M, seq);
  spec_kernel<<<dim3(32, 256), 256, 0, stream>>>(seq, out);
}